// Round 1
// baseline (306.534 us; speedup 1.0000x reference)
//
#include <hip/hip_runtime.h>
#include <math.h>

#define TT 2048
#define NN 8192
#define DD 4
#define HH 128

// ---------------------------------------------------------------------------
// Stage 1: per-timestep MLP -> A, stored TRANSPOSED: A_t[e*TT + t], e in [0,16)
// One block per timestep, HH=128 threads.
// ---------------------------------------------------------------------------
__global__ void mlp_kernel(const float* __restrict__ t_arr,
                           const float* __restrict__ M0,
                           const float* __restrict__ W1, const float* __restrict__ b1,
                           const float* __restrict__ W2, const float* __restrict__ b2,
                           const float* __restrict__ W3, const float* __restrict__ b3,
                           float* __restrict__ A_t) {
    const int t = blockIdx.x;
    const int j = threadIdx.x;
    __shared__ float h1[HH];
    __shared__ float h2[HH];

    const float t_cur  = t_arr[t];
    const float t_prev = (t > 0) ? t_arr[t - 1] : 0.0f;
    const float dt = t_cur - t_prev;
    const float ta = 0.5f * (t_cur + t_prev);

    // layer 1: input dim is 1 -> h1[j] = tanh(ta * W1[j] + b1[j])
    h1[j] = tanhf(fmaf(ta, W1[j], b1[j]));
    __syncthreads();

    // layer 2: h2[j] = tanh(sum_i h1[i] * W2[i*H + j] + b2[j])   (coalesced over j)
    float acc = b2[j];
    #pragma unroll 8
    for (int i = 0; i < HH; ++i) acc = fmaf(h1[i], W2[i * HH + j], acc);
    h2[j] = tanhf(acc);
    __syncthreads();

    // layer 3: 16 outputs; A[t][e] = (sum_i h2[i]*W3[i*16+e] + b3[e] + M0[e]) * dt
    if (j < 16) {
        float a = b3[j];
        #pragma unroll 8
        for (int i = 0; i < HH; ++i) a = fmaf(h2[i], W3[i * 16 + j], a);
        a = (a + M0[j]) * dt;
        A_t[j * TT + t] = a;   // transposed layout for contiguous scan loads
    }
}

// ---------------------------------------------------------------------------
// Stage 2: cumsum over t of the 16 element-sequences.
// Single block, 1024 threads: e = tid/64 (16 elements), c = tid%64 (64 chunks
// of 32 contiguous steps). Chunk-sum -> LDS exclusive scan -> re-emit.
// Output layout: Asum[t*16 + e] (row-per-timestep, ready for expm).
// ---------------------------------------------------------------------------
__global__ void scan_kernel(const float* __restrict__ A_t, float* __restrict__ Asum) {
    const int tid = threadIdx.x;
    const int e = tid >> 6;        // 0..15
    const int c = tid & 63;        // 0..63
    const float* src = A_t + e * TT + c * 32;

    float v[32];
    float s = 0.0f;
    #pragma unroll
    for (int i = 0; i < 32; ++i) { v[i] = src[i]; s += v[i]; }

    __shared__ float cs[16 * 64];
    cs[e * 64 + c] = s;
    __syncthreads();

    if (c == 0) {  // 16 serial leaders, 64 steps each: exclusive scan
        float run = 0.0f;
        const int base = e * 64;
        for (int i = 0; i < 64; ++i) {
            const float x = cs[base + i];
            cs[base + i] = run;
            run += x;
        }
    }
    __syncthreads();

    float run = cs[e * 64 + c];
    const int t0 = c * 32;
    #pragma unroll
    for (int i = 0; i < 32; ++i) {
        run += v[i];
        Asum[(t0 + i) * 16 + e] = run;
    }
}

// ---------------------------------------------------------------------------
// Stage 3: batched 4x4 expm via scaling-and-squaring + Taylor(12).
// One thread per timestep.
// ---------------------------------------------------------------------------
__device__ __forceinline__ void mm4(const float* __restrict__ A,
                                    const float* __restrict__ B,
                                    float* __restrict__ C) {
    #pragma unroll
    for (int i = 0; i < 4; ++i) {
        #pragma unroll
        for (int j = 0; j < 4; ++j) {
            float s = 0.0f;
            #pragma unroll
            for (int k = 0; k < 4; ++k) s = fmaf(A[i * 4 + k], B[k * 4 + j], s);
            C[i * 4 + j] = s;
        }
    }
}

__global__ void expm_kernel(const float* __restrict__ Asum, float* __restrict__ E) {
    const int t = blockIdx.x * blockDim.x + threadIdx.x;
    if (t >= TT) return;

    float M[16];
    const float4* src = (const float4*)(Asum + t * 16);
    #pragma unroll
    for (int r = 0; r < 4; ++r) {
        float4 v = src[r];
        M[r * 4 + 0] = v.x; M[r * 4 + 1] = v.y; M[r * 4 + 2] = v.z; M[r * 4 + 3] = v.w;
    }

    // inf-norm (max abs row sum)
    float nrm = 0.0f;
    #pragma unroll
    for (int i = 0; i < 4; ++i) {
        float rs = fabsf(M[i*4+0]) + fabsf(M[i*4+1]) + fabsf(M[i*4+2]) + fabsf(M[i*4+3]);
        nrm = fmaxf(nrm, rs);
    }
    int k = 0;
    while (nrm > 0.5f && k < 40) { nrm *= 0.5f; ++k; }
    const float sc = ldexpf(1.0f, -k);
    #pragma unroll
    for (int i = 0; i < 16; ++i) M[i] *= sc;

    // Taylor: R = I + M + M^2/2! + ... + M^12/12!
    float R[16], P[16], Q[16];
    #pragma unroll
    for (int i = 0; i < 16; ++i) { P[i] = M[i]; R[i] = M[i]; }
    R[0] += 1.0f; R[5] += 1.0f; R[10] += 1.0f; R[15] += 1.0f;
    for (int n = 2; n <= 12; ++n) {
        mm4(P, M, Q);
        const float inv = 1.0f / (float)n;
        #pragma unroll
        for (int i = 0; i < 16; ++i) { P[i] = Q[i] * inv; R[i] += P[i]; }
    }
    // square k times
    for (int s = 0; s < k; ++s) {
        mm4(R, R, Q);
        #pragma unroll
        for (int i = 0; i < 16; ++i) R[i] = Q[i];
    }

    float4* dst = (float4*)(E + t * 16);
    #pragma unroll
    for (int r = 0; r < 4; ++r)
        dst[r] = make_float4(R[r*4+0], R[r*4+1], R[r*4+2], R[r*4+3]);
}

// ---------------------------------------------------------------------------
// Stage 4: out[t,n,:] = E[t] @ x[n].  256 MB write-bound epilogue.
// grid (NN/256, TT), 256 threads; one float4 load + one float4 store per thread.
// ---------------------------------------------------------------------------
__global__ void apply_kernel(const float* __restrict__ E,
                             const float* __restrict__ x,
                             float* __restrict__ out) {
    const int t = blockIdx.y;
    const int n = blockIdx.x * blockDim.x + threadIdx.x;

    __shared__ float Es[16];
    if (threadIdx.x < 16) Es[threadIdx.x] = E[t * 16 + threadIdx.x];
    __syncthreads();

    const float4 xv = ((const float4*)x)[n];
    float4 o;
    o.x = fmaf(Es[0],  xv.x, fmaf(Es[1],  xv.y, fmaf(Es[2],  xv.z, Es[3]  * xv.w)));
    o.y = fmaf(Es[4],  xv.x, fmaf(Es[5],  xv.y, fmaf(Es[6],  xv.z, Es[7]  * xv.w)));
    o.z = fmaf(Es[8],  xv.x, fmaf(Es[9],  xv.y, fmaf(Es[10], xv.z, Es[11] * xv.w)));
    o.w = fmaf(Es[12], xv.x, fmaf(Es[13], xv.y, fmaf(Es[14], xv.z, Es[15] * xv.w)));

    ((float4*)out)[(size_t)t * NN + n] = o;
}

// ---------------------------------------------------------------------------
extern "C" void kernel_launch(void* const* d_in, const int* in_sizes, int n_in,
                              void* d_out, int out_size, void* d_ws, size_t ws_size,
                              hipStream_t stream) {
    const float* x  = (const float*)d_in[0];   // (N, D)
    const float* t  = (const float*)d_in[1];   // (T,)
    const float* M0 = (const float*)d_in[2];   // (D, D) zeros
    const float* W1 = (const float*)d_in[3];   // (1, H)
    const float* b1 = (const float*)d_in[4];   // (H,)
    const float* W2 = (const float*)d_in[5];   // (H, H)
    const float* b2 = (const float*)d_in[6];   // (H,)
    const float* W3 = (const float*)d_in[7];   // (H, 16)
    const float* b3 = (const float*)d_in[8];   // (16,)
    float* out = (float*)d_out;                // (T, N, D) f32

    float* A_t  = (float*)d_ws;                // 16*T floats, transposed
    float* Asum = A_t  + 16 * TT;              // 16*T floats, (T,16)
    float* E    = Asum + 16 * TT;              // 16*T floats, (T,16)

    mlp_kernel<<<TT, HH, 0, stream>>>(t, M0, W1, b1, W2, b2, W3, b3, A_t);
    scan_kernel<<<1, 1024, 0, stream>>>(A_t, Asum);
    expm_kernel<<<TT / 256, 256, 0, stream>>>(Asum, E);
    apply_kernel<<<dim3(NN / 256, TT), 256, 0, stream>>>(E, x, out);
}